// Round 30
// baseline (183.337 us; speedup 1.0000x reference)
//
#include <hip/hip_runtime.h>
#include <hip/hip_fp16.h>
#include <float.h>
#include <math.h>

#define HH 40
#define WW 128
#define PP 5120
#define NN 5120
#define CC 128
#define KK 25
#define SPOT 5
#define NEGV -1e8f

#define CSPL 8
#define NSEG 16
#define NRT (PP / 64)            // 80 row tiles (transpose-side partials)
#define EPS  1e-4f
#define LOSC 2048.0f
#define RSEGS 16
#define RSEGL (NN / RSEGS)
#define NRMB ((PP + NN) / 4)     // normalize-role blocks in k_prep

typedef _Float16 half8 __attribute__((ext_vector_type(8)));
typedef float f32x4 __attribute__((ext_vector_type(4)));

// ---------------- K1+K2 fused: normalize (blocks 0..NRMB-1) || knn (rest) --------
__global__ __launch_bounds__(256) void k_prep(const float* __restrict__ imf,
                                              const float* __restrict__ pcf,
                                              const float* __restrict__ pts,
                                              float* __restrict__ imn, float* __restrict__ pcn,
                                              __half* __restrict__ imh, __half* __restrict__ iml,
                                              __half* __restrict__ pch, __half* __restrict__ pcl,
                                              int* __restrict__ nb, int* __restrict__ cnt) {
    __shared__ int hist[256];
    __shared__ int wsum2[2][4];
    __shared__ int wsum[4];
    __shared__ int wmin[4];
    __shared__ int s_b, s_need, s_cntLess;
    __shared__ unsigned long long sel[32];
    int t = threadIdx.x;
    int wid = t >> 6, lane = t & 63;

    if (blockIdx.x < NRMB) {
        // ---------------- normalize role ----------------
        if (blockIdx.x == 0 && t < 4) cnt[t] = 0;
        int row = blockIdx.x * 4 + wid;
        const float* src; float* dst; __half* dh; __half* dl; int r;
        if (row < PP) { src = imf; dst = imn; dh = imh; dl = iml; r = row; }
        else          { src = pcf; dst = pcn; dh = pch; dl = pcl; r = row - PP; }
        float2 v = *(const float2*)&src[r * CC + lane * 2];
        double ss = (double)v.x * (double)v.x + (double)v.y * (double)v.y;
#pragma unroll
        for (int o = 32; o; o >>= 1) ss += __shfl_xor(ss, o);
        double inv = 1.0 / fmax(sqrt(ss), 1e-12);
        float2 o2 = make_float2((float)((double)v.x * inv), (float)((double)v.y * inv));
        *(float2*)&dst[r * CC + lane * 2] = o2;
        __half hx = __float2half_rn(o2.x), hy = __float2half_rn(o2.y);
        float rx = o2.x - __half2float(hx), ry = o2.y - __half2float(hy);
        __half2 hh; hh.x = hx; hh.y = hy;
        __half2 ll; ll.x = __float2half_rn(rx * LOSC); ll.y = __float2half_rn(ry * LOSC);
        *(__half2*)&dh[r * CC + lane * 2] = hh;
        *(__half2*)&dl[r * CC + lane * 2] = ll;
        return;
    }

    // ---------------- knn role ----------------
    int i = blockIdx.x - NRMB;
    float px = pts[i * 3 + 0], py = pts[i * 3 + 1], pz = pts[i * 3 + 2];

    unsigned k[20];
#pragma unroll
    for (int e = 0; e < 20; ++e) {
        int j = e * 256 + t;
        float dx = __fsub_rn(px, pts[j * 3 + 0]);
        float dy = __fsub_rn(py, pts[j * 3 + 1]);
        float dz = __fsub_rn(pz, pts[j * 3 + 2]);
        float s = __fadd_rn(__fadd_rn(__fmul_rn(dx, dx), __fmul_rn(dy, dy)),
                            __fmul_rn(dz, dz));
        k[e] = __float_as_uint(s);
    }

    int need = KK;
    unsigned bpre = 0;
    for (int bit = 7; bit >= 0; --bit) {
        int c = 0;
        unsigned want = bpre << 1;
#pragma unroll
        for (int e = 0; e < 20; ++e)
            c += ((k[e] >> (24 + bit)) == want);
#pragma unroll
        for (int o = 32; o; o >>= 1) c += __shfl_xor(c, o);
        int par = bit & 1;
        if (lane == 0) wsum2[par][wid] = c;
        __syncthreads();
        int tot = wsum2[par][0] + wsum2[par][1] + wsum2[par][2] + wsum2[par][3];
        if (tot >= need) bpre = want;
        else { bpre = want | 1; need -= tot; }
    }
    unsigned prefix = bpre << 24;

    for (int l = 1; l < 4; ++l) {
        int shift = 24 - 8 * l;
        hist[t] = 0;
        __syncthreads();
        unsigned pmask = 0xFFFFFFFFu << (shift + 8);
#pragma unroll
        for (int e = 0; e < 20; ++e)
            if ((k[e] & pmask) == prefix)
                atomicAdd(&hist[(k[e] >> shift) & 255], 1);
        __syncthreads();
        int v = hist[t], c = v;
#pragma unroll
        for (int o = 1; o < 64; o <<= 1) {
            int u = __shfl_up(c, o);
            if (lane >= o) c += u;
        }
        if (lane == 63) wsum[wid] = c;
        __syncthreads();
        for (int wv = 0; wv < wid; ++wv) c += wsum[wv];
        int cex = c - v;
        if (cex < need && c >= need) { s_b = t; s_need = need - cex; }
        __syncthreads();
        prefix |= ((unsigned)s_b) << shift;
        need = s_need;
        __syncthreads();
    }

    unsigned K = prefix;
    int needK = need;

    if (t == 0) s_cntLess = 0;
    __syncthreads();
#pragma unroll
    for (int e = 0; e < 20; ++e) {
        if (k[e] < K) {
            int slot = atomicAdd(&s_cntLess, 1);
            if (slot < 32)
                sel[slot] = ((unsigned long long)k[e] << 32) | (unsigned)(e * 256 + t);
        }
    }
    __syncthreads();
    int nl = s_cntLess;

    if (t < nl) {
        unsigned long long mine = sel[t];
        int rk = 0;
        for (int s = 0; s < nl; ++s) rk += (sel[s] < mine);
        nb[i * KK + rk] = (int)(mine & 0xFFFFFFFFull);
    }

    unsigned tmask = 0;
#pragma unroll
    for (int e = 0; e < 20; ++e)
        if (k[e] == K) tmask |= 1u << e;

    for (int q = 0; q < needK; ++q) {
        int mi = tmask ? ((__ffs(tmask) - 1) * 256 + t) : 0x7fffffff;
#pragma unroll
        for (int o = 32; o; o >>= 1) mi = min(mi, __shfl_xor(mi, o));
        if (lane == 0) wmin[wid] = mi;
        __syncthreads();
        int g = min(min(wmin[0], wmin[1]), min(wmin[2], wmin[3]));
        if (t == 0) nb[i * KK + nl + q] = g;
        if ((g & 255) == t) tmask &= ~(1u << (g >> 8));
        __syncthreads();
    }
}

// ---------------- K3: split-fp16 MFMA screen, SINGLE GEMM, both-axis reduce ------
// S = imh_split x pch_split^T computed ONCE (was twice, z=0/1). Per block
// (64 rows x 640-col segment): existing per-row (v1,v2,i1) over cols PLUS
// per-col top-2 over the 64-row tile (thread scan -> shfl butterfly over lg ->
// parity-dbuf LDS merge across wrow waves) stored to pvalT/pv2T/pidxT[tile][col].
// Anywhere old/new fp32 rounding could disagree the gap is < EPS -> flagged ->
// fp64 recheck: final outputs identical. MFMA count, staging, A-loads all halve.
__global__ __launch_bounds__(256) void k_rowmax(const __half* __restrict__ imh,
                                                const __half* __restrict__ iml,
                                                const __half* __restrict__ pch,
                                                const __half* __restrict__ pcl,
                                                float* __restrict__ pval,
                                                float* __restrict__ pv2,
                                                int* __restrict__ pidx,
                                                float* __restrict__ pvalT,
                                                float* __restrict__ pv2T,
                                                int* __restrict__ pidxT) {
    const __half* Ah = imh;
    const __half* Al = iml;
    const __half* Bh = pch;
    const __half* Bl = pcl;
    __shared__ char sB[2 * 32768];     // [buf][Bh 16KB | Bl 16KB], 64 rows x 256B
    __shared__ float sCv1[2][4][2][16];
    __shared__ float sCv2[2][4][2][16];
    __shared__ int   sCi [2][4][2][16];

    int t = threadIdx.x;
    int wave = t >> 6, l = t & 63;
    int wrow = wave >> 1, wcol = wave & 1;
    int lg = l >> 4, lc = l & 15;
    int rb = blockIdx.x * 64;
    const int segLen = NN / CSPL;      // 640
    const int nCh = segLen / 64;       // 10
    int segbase = blockIdx.y * segLen;
    int srow = l >> 4;
    int sblk = l & 15;

    half8 Afh[2][4], Afl[2][4];
#pragma unroll
    for (int rt = 0; rt < 2; ++rt)
#pragma unroll
        for (int ks = 0; ks < 4; ++ks) {
            int row = rb + wrow * 32 + rt * 16 + lc;
            int ho = ks * 32 + lg * 8;
            Afh[rt][ks] = *(const half8*)&Ah[(size_t)row * CC + ho];
            Afl[rt][ks] = *(const half8*)&Al[(size_t)row * CC + ho];
        }

    float v1[2][4], v2[2][4]; int i1[2][4];
#pragma unroll
    for (int rt = 0; rt < 2; ++rt)
#pragma unroll
        for (int rg = 0; rg < 4; ++rg) { v1[rt][rg] = -1e30f; v2[rt][rg] = -1e30f; i1[rt][rg] = 0; }

    auto stage = [&](int bufsel, int chbase) {
#pragma unroll
        for (int b = 0; b < 4; ++b) {
            int rbase = wave * 16 + b * 4;
            int r = rbase + srow;
            int gblk = sblk ^ (r & 7);
            __builtin_amdgcn_global_load_lds(
                (const __attribute__((address_space(1))) void*)
                    &Bh[(size_t)(chbase + r) * CC + gblk * 8],
                (__attribute__((address_space(3))) void*)
                    (sB + bufsel * 32768 + rbase * 256),
                16, 0, 0);
            __builtin_amdgcn_global_load_lds(
                (const __attribute__((address_space(1))) void*)
                    &Bl[(size_t)(chbase + r) * CC + gblk * 8],
                (__attribute__((address_space(3))) void*)
                    (sB + bufsel * 32768 + 16384 + rbase * 256),
                16, 0, 0);
        }
    };

    stage(0, segbase);
    __syncthreads();

    int cur = 0;
    for (int c = 0; c < nCh; ++c) {
        if (c + 1 < nCh) stage(cur ^ 1, segbase + (c + 1) * 64);

        f32x4 aH[2][2], aX[2][2];
#pragma unroll
        for (int rt = 0; rt < 2; ++rt)
#pragma unroll
            for (int ct = 0; ct < 2; ++ct) {
                aH[rt][ct] = (f32x4){0.f, 0.f, 0.f, 0.f};
                aX[rt][ct] = (f32x4){0.f, 0.f, 0.f, 0.f};
            }

        const char* bufp = sB + cur * 32768;
#pragma unroll
        for (int ks = 0; ks < 4; ++ks) {
            int kb = ks * 64 + lg * 16;
            half8 bh[2], bl[2];
#pragma unroll
            for (int ct = 0; ct < 2; ++ct) {
                int row = wcol * 32 + ct * 16 + lc;
                int off = row * 256 + (kb ^ ((row & 7) << 4));
                bh[ct] = *(const half8*)(bufp + off);
                bl[ct] = *(const half8*)(bufp + 16384 + off);
            }
#pragma unroll
            for (int rt = 0; rt < 2; ++rt)
#pragma unroll
                for (int ct = 0; ct < 2; ++ct) {
                    aH[rt][ct] = __builtin_amdgcn_mfma_f32_16x16x32_f16(
                        Afh[rt][ks], bh[ct], aH[rt][ct], 0, 0, 0);
                    aX[rt][ct] = __builtin_amdgcn_mfma_f32_16x16x32_f16(
                        Afh[rt][ks], bl[ct], aX[rt][ct], 0, 0, 0);
                    aX[rt][ct] = __builtin_amdgcn_mfma_f32_16x16x32_f16(
                        Afl[rt][ks], bh[ct], aX[rt][ct], 0, 0, 0);
                }
        }

        // ---- epilogue: row-max update + per-col top-2 over this 64-row tile ----
        float cv1[2] = {-1e30f, -1e30f}, cv2[2] = {-1e30f, -1e30f};
        int   ci1[2] = {0, 0};
#pragma unroll
        for (int rt = 0; rt < 2; ++rt)
#pragma unroll
            for (int ct = 0; ct < 2; ++ct) {
                int col = segbase + c * 64 + wcol * 32 + ct * 16 + lc;
#pragma unroll
                for (int rg = 0; rg < 4; ++rg) {
                    float v = aH[rt][ct][rg] + aX[rt][ct][rg] * (1.0f / LOSC);
                    bool gt = v > v1[rt][rg];
                    v2[rt][rg] = gt ? v1[rt][rg] : fmaxf(v2[rt][rg], v);
                    i1[rt][rg] = gt ? col : i1[rt][rg];
                    v1[rt][rg] = gt ? v : v1[rt][rg];
                    int grow = rb + wrow * 32 + rt * 16 + lg * 4 + rg;
                    bool cgt = v > cv1[ct];
                    cv2[ct] = cgt ? cv1[ct] : fmaxf(cv2[ct], v);
                    ci1[ct] = cgt ? grow : ci1[ct];
                    cv1[ct] = cgt ? v : cv1[ct];
                }
            }
        // butterfly over lg lanes (xor 16, 32): same col, different row groups
#pragma unroll
        for (int ct = 0; ct < 2; ++ct) {
#pragma unroll
            for (int o = 16; o < 64; o <<= 1) {
                float o1 = __shfl_xor(cv1[ct], o);
                float o2v = __shfl_xor(cv2[ct], o);
                int   oi = __shfl_xor(ci1[ct], o);
                if (o1 > cv1[ct]) { cv2[ct] = fmaxf(cv1[ct], o2v); cv1[ct] = o1; ci1[ct] = oi; }
                else              { cv2[ct] = fmaxf(cv2[ct], o1); }
            }
        }
        int par = c & 1;
        if (lg == 0) {
#pragma unroll
            for (int ct = 0; ct < 2; ++ct) {
                sCv1[par][wave][ct][lc] = cv1[ct];
                sCv2[par][wave][ct][lc] = cv2[ct];
                sCi [par][wave][ct][lc] = ci1[ct];
            }
        }
        __syncthreads();   // releases cur reads, completes DMA, publishes sC*

        if (wrow == 0 && lg == 0) {   // waves 0,1 merge wrow0+wrow1 for their wcol
#pragma unroll
            for (int ct = 0; ct < 2; ++ct) {
                float a1 = sCv1[par][wave][ct][lc];
                float a2 = sCv2[par][wave][ct][lc];
                int   ai = sCi [par][wave][ct][lc];
                float b1 = sCv1[par][wave + 2][ct][lc];
                float b2 = sCv2[par][wave + 2][ct][lc];
                int   bi = sCi [par][wave + 2][ct][lc];
                float m1, m2; int mi;
                if (b1 > a1) { m1 = b1; mi = bi; m2 = fmaxf(a1, b2); }
                else         { m1 = a1; mi = ai; m2 = fmaxf(a2, b1); }
                int col = segbase + c * 64 + wcol * 32 + ct * 16 + lc;
                size_t o = (size_t)blockIdx.x * NN + col;
                pvalT[o] = m1; pv2T[o] = m2; pidxT[o] = mi;
            }
        }
        cur ^= 1;
    }

#pragma unroll
    for (int rt = 0; rt < 2; ++rt)
#pragma unroll
        for (int rg = 0; rg < 4; ++rg) {
            float a1 = v1[rt][rg], a2 = v2[rt][rg]; int ai = i1[rt][rg];
#pragma unroll
            for (int o = 1; o < 16; o <<= 1) {
                float o1 = __shfl_xor(a1, o);
                float o2v = __shfl_xor(a2, o);
                int   oi = __shfl_xor(ai, o);
                if (o1 > a1) { a2 = fmaxf(a1, o2v); a1 = o1; ai = oi; }
                else         { a2 = fmaxf(a2, o1); }
            }
            if (lc == 0) {
                int seg = blockIdx.y * 2 + wcol;
                size_t o = (size_t)seg * PP
                         + rb + wrow * 32 + rt * 16 + lg * 4 + rg;
                pval[o] = a1; pv2[o] = a2; pidx[o] = ai;
            }
        }
}

// ---------------- K3b+K3e fused: partial-reduce (16 or 80) + exact fp64 value ----
__global__ void k_reduce_exact(const float* __restrict__ pval, const float* __restrict__ pv2,
                               const int* __restrict__ pidx,
                               const float* __restrict__ pvalT, const float* __restrict__ pv2T,
                               const int* __restrict__ pidxT,
                               const float* __restrict__ imn, const float* __restrict__ pcn,
                               int* __restrict__ bestI, int* __restrict__ bestPI,
                               double* __restrict__ bestSd, double* __restrict__ bestPSd,
                               int* __restrict__ list2, int* __restrict__ cnt) {
    int wid = threadIdx.x >> 6, lane = threadIdx.x & 63;
    int row = blockIdx.x * 4 + wid;
    int side = (row >= PP) ? 1 : 0;
    int r = side ? (row - PP) : row;

    float v1 = -1e30f, v2 = -1e30f; int i1 = 0x7fffffff;
    if (side == 0) {
        if (lane < NSEG) {
            v1 = pval[(size_t)lane * PP + r];
            v2 = pv2[(size_t)lane * PP + r];
            i1 = pidx[(size_t)lane * PP + r];
        }
    } else {
        v1 = pvalT[(size_t)lane * NN + r];
        v2 = pv2T[(size_t)lane * NN + r];
        i1 = pidxT[(size_t)lane * NN + r];
        if (lane < NRT - 64) {
            float o1 = pvalT[(size_t)(64 + lane) * NN + r];
            float o2v = pv2T[(size_t)(64 + lane) * NN + r];
            int   oi = pidxT[(size_t)(64 + lane) * NN + r];
            if (o1 > v1) { v2 = fmaxf(v1, o2v); v1 = o1; i1 = oi; }
            else         { v2 = fmaxf(v2, o1); }
        }
    }
#pragma unroll
    for (int o = 1; o < 64; o <<= 1) {
        float o1 = __shfl_xor(v1, o);
        float o2v = __shfl_xor(v2, o);
        int   oi = __shfl_xor(i1, o);
        if (o1 > v1) { v2 = fmaxf(v1, o2v); v1 = o1; i1 = oi; }
        else         { v2 = fmaxf(v2, o1); }
    }
    int bi = __shfl(i1, 0);
    float b1 = __shfl(v1, 0), b2 = __shfl(v2, 0);

    const float* A = side ? pcn : imn;
    const float* B = side ? imn : pcn;
    float2 av = *(const float2*)&A[(size_t)r * CC + lane * 2];
    float2 bv = *(const float2*)&B[(size_t)bi * CC + lane * 2];
    double s = (double)av.x * (double)bv.x + (double)av.y * (double)bv.y;
#pragma unroll
    for (int o = 32; o; o >>= 1) s += __shfl_xor(s, o);

    if (lane == 0) {
        if (side == 0) { bestI[r] = bi; bestSd[r] = s; }
        else           { bestPI[r] = bi; bestPSd[r] = s; }
        if (b1 - b2 < EPS) {
            int slot = atomicAdd(&cnt[0], 1);
            list2[slot] = r | (side << 16);
        }
    }
}

// ---------------- K3f-a: fp64 repair, split 16 column-segments per flagged row ---
__global__ void k_recheck64a(const float* __restrict__ imn, const float* __restrict__ pcn,
                             const int* __restrict__ list2, const int* __restrict__ cnt,
                             double* __restrict__ rqv, int* __restrict__ rqi) {
    __shared__ double ad[CC];
    __shared__ double rv[4];
    __shared__ int    ri[4];
    int seg = blockIdx.x, t = threadIdx.x;
    int wid = t >> 6, lane = t & 63;
    int total = cnt[0];
    for (int e = blockIdx.y; e < total; e += gridDim.y) {
        __syncthreads();
        int ent = list2[e];
        int r = ent & 0xffff, side = ent >> 16;
        const float* Arow = (side == 0 ? imn : pcn) + (size_t)r * CC;
        const float* B    = (side == 0 ? pcn : imn);
        if (t < CC) ad[t] = (double)Arow[t];
        __syncthreads();
        double bv = -1e300; int bi = 0x7fffffff;
        for (int j = seg * RSEGL + t; j < (seg + 1) * RSEGL; j += 256) {
            double s0 = 0.0, s1 = 0.0, s2 = 0.0, s3 = 0.0;
#pragma unroll 8
            for (int c4 = 0; c4 < CC / 4; ++c4) {
                float4 b = *(const float4*)&B[(size_t)j * CC + c4 * 4];
                s0 += ad[c4 * 4 + 0] * (double)b.x;
                s1 += ad[c4 * 4 + 1] * (double)b.y;
                s2 += ad[c4 * 4 + 2] * (double)b.z;
                s3 += ad[c4 * 4 + 3] * (double)b.w;
            }
            double s = (s0 + s1) + (s2 + s3);
            if (s > bv || (s == bv && j < bi)) { bv = s; bi = j; }
        }
#pragma unroll
        for (int o = 32; o; o >>= 1) {
            double ov = __shfl_xor(bv, o); int oi = __shfl_xor(bi, o);
            if (ov > bv || (ov == bv && oi < bi)) { bv = ov; bi = oi; }
        }
        if (lane == 0) { rv[wid] = bv; ri[wid] = bi; }
        __syncthreads();
        if (t == 0) {
            for (int wv = 1; wv < 4; ++wv)
                if (rv[wv] > bv || (rv[wv] == bv && ri[wv] < bi)) { bv = rv[wv]; bi = ri[wv]; }
            rqv[(size_t)e * RSEGS + seg] = bv;
            rqi[(size_t)e * RSEGS + seg] = bi;
        }
        __syncthreads();
    }
}

// ---------------- K3f-b: reduce the 16 segment partials per entry ----------------
__global__ void k_recheck64b(const int* __restrict__ list2, const int* __restrict__ cnt,
                             const double* __restrict__ rqv, const int* __restrict__ rqi,
                             double* __restrict__ bestSd, int* __restrict__ bestI,
                             double* __restrict__ bestPSd, int* __restrict__ bestPI) {
    int e = blockIdx.x * 256 + threadIdx.x;
    if (e >= cnt[0]) return;
    double bv = rqv[(size_t)e * RSEGS]; int bi = rqi[(size_t)e * RSEGS];
#pragma unroll 4
    for (int s = 1; s < RSEGS; ++s) {
        double ov = rqv[(size_t)e * RSEGS + s]; int oi = rqi[(size_t)e * RSEGS + s];
        if (ov > bv || (ov == bv && oi < bi)) { bv = ov; bi = oi; }
    }
    int ent = list2[e];
    int r = ent & 0xffff, side = ent >> 16;
    if (side == 0) { bestSd[r] = bv; bestI[r] = bi; }
    else           { bestPSd[r] = bv; bestPI[r] = bi; }
}

// ---------------- WAVE-PARALLEL bitmap -> stable top-125 compaction --------------
__device__ __forceinline__ void compact_bits_par(const unsigned* bits,
                                                 float* __restrict__ sm,
                                                 float* __restrict__ si, int lane) {
    unsigned w0 = bits[lane];
    unsigned w1 = bits[64 + lane];
    unsigned w2 = (lane < 32) ? bits[128 + lane] : 0u;
    int c0 = __popc(w0), c1 = __popc(w1), c2 = __popc(w2);
    int s0 = c0, s1 = c1, s2 = c2;
#pragma unroll
    for (int o = 1; o < 64; o <<= 1) {
        int u0 = __shfl_up(s0, o); if (lane >= o) s0 += u0;
        int u1 = __shfl_up(s1, o); if (lane >= o) s1 += u1;
        int u2 = __shfl_up(s2, o); if (lane >= o) s2 += u2;
    }
    int tot0 = __shfl(s0, 63);
    int tot1 = __shfl(s1, 63);
    int tot2 = __shfl(s2, 31);
    int nl = tot0 + tot1 + tot2;
    int e0 = s0 - c0;
    int e1 = tot0 + (s1 - c1);
    int e2 = tot0 + tot1 + (s2 - c2);

    {
        int base = e0; unsigned word = w0; int wi = lane;
        while (word) { int pos = __ffs(word) - 1;
            si[base] = (float)(wi * 32 + pos); sm[base] = 1.0f; word &= word - 1; ++base; }
        base = e1; word = w1; wi = 64 + lane;
        while (word) { int pos = __ffs(word) - 1;
            si[base] = (float)(wi * 32 + pos); sm[base] = 1.0f; word &= word - 1; ++base; }
        if (lane < 32) {
            base = e2; word = w2; wi = 128 + lane;
            while (word) { int pos = __ffs(word) - 1;
                si[base] = (float)(wi * 32 + pos); sm[base] = 1.0f; word &= word - 1; ++base; }
        }
    }
    {
        int wi = lane; int base = nl + 32 * wi - e0; unsigned word = ~w0;
        while (word && base < 125) { int pos = __ffs(word) - 1;
            si[base] = (float)(wi * 32 + pos); sm[base] = 0.0f; word &= word - 1; ++base; }
        wi = 64 + lane; base = nl + 32 * wi - e1; word = ~w1;
        while (word && base < 125) { int pos = __ffs(word) - 1;
            si[base] = (float)(wi * 32 + pos); sm[base] = 0.0f; word &= word - 1; ++base; }
        if (lane < 32) {
            wi = 128 + lane; base = nl + 32 * wi - e2; word = ~w2;
            while (word && base < 125) { int pos = __ffs(word) - 1;
                si[base] = (float)(wi * 32 + pos); sm[base] = 0.0f; word &= word - 1; ++base; }
        }
    }
}

// ---------------- K4..K7 fused: select + spot ------------------------------------
__global__ void k_select_spot(const float* __restrict__ imn, const float* __restrict__ pcn,
                              const int* __restrict__ nb,
                              const double* __restrict__ bestSd, const int* __restrict__ bestI,
                              const double* __restrict__ bestPSd, const int* __restrict__ bestPI,
                              float* __restrict__ outSelect,
                              float* __restrict__ outMask, float* __restrict__ outIdx,
                              float* __restrict__ outMaskPc, float* __restrict__ outIdxPc) {
    __shared__ unsigned bits[4][160];
    __shared__ float smv[4][125];
    __shared__ float siv[4][125];
    int t = threadIdx.x;
    int wid = t >> 6, lane = t & 63;
    int bid = blockIdx.x;

    if (bid < PP / 4) {
        // ---------------- image role ----------------
        int pb = (bid & 7) * (PP / 4 / 8) + (bid >> 3);   // XCD-chunked
        int p = pb * 4 + wid;
        int h = p >> 7, w = p & 127;

        double mysim = -1e300;
        if (lane < KK) {
            int di = lane / 5 - 2, dj = lane % 5 - 2;
            int hc = min(max(h + di, 0), HH - 1);
            int wc = min(max(w + dj, 0), WW - 1);
            const float* crow = &imn[(size_t)p * CC];
            const float* nrow = &imn[(size_t)(hc * WW + wc) * CC];
            double s0 = 0.0, s1 = 0.0, s2 = 0.0, s3 = 0.0;
#pragma unroll 8
            for (int c = 0; c < CC; c += 4) {
                float4 cv = *(const float4*)&crow[c];
                float4 nv = *(const float4*)&nrow[c];
                s0 += (double)cv.x * (double)nv.x;
                s1 += (double)cv.y * (double)nv.y;
                s2 += (double)cv.z * (double)nv.z;
                s3 += (double)cv.w * (double)nv.w;
            }
            mysim = (s0 + s1) + (s2 + s3);
        }
        double mx = mysim;
#pragma unroll
        for (int o = 1; o < 64; o <<= 1) mx = fmax(mx, __shfl_xor(mx, o));

        double e = 0.0;
        if (lane < KK) e = exp(mysim - mx);
        double sum = e;
#pragma unroll
        for (int o = 32; o; o >>= 1) sum += __shfl_xor(sum, o);
        double inv = 1.0 / sum;

        double selv = -1e300;
        if (lane < KK) {
            int di = lane / 5 - 2, dj = lane % 5 - 2;
            int h2 = h + di, w2 = w + dj;
            bool valid = (h2 >= 0 && h2 < HH && w2 >= 0 && w2 < WW);
            int hc = min(max(h2, 0), HH - 1), wc = min(max(w2, 0), WW - 1);
            double conf = bestSd[hc * WW + wc];
            double so = valid ? (e * inv * conf) : (double)NEGV;
            outSelect[lane * PP + p] = (float)so;
            selv = (lane == 12) ? (double)NEGV : so;
        }

        int tks[5]; tks[0] = 12;
        double sv = selv; int sk = (lane < KK) ? lane : 63;
#pragma unroll
        for (int s = 0; s < 4; ++s) {
            double bv = sv; int bk = sk;
#pragma unroll
            for (int o = 1; o < 64; o <<= 1) {
                double ov = __shfl_xor(bv, o);
                int ok = __shfl_xor(bk, o);
                if (ov > bv || (ov == bv && ok < bk)) { bv = ov; bk = ok; }
            }
            tks[s + 1] = bk;
            if (sk == bk) sv = -1e300;
        }

        int sd0, sd1, sd2, sd3, sd4;
#pragma unroll
        for (int s = 0; s < 5; ++s) {
            int k = tks[s];
            int di = k / 5 - 2, dj = k % 5 - 2;
            int h2 = h + di, w2 = w + dj;
            int pix = (h2 >= 0 && h2 < HH && w2 >= 0 && w2 < WW) ? (h2 * WW + w2) : -1;
            pix = min(max(pix, 0), PP - 1);
            int sd = bestI[pix];
            if (s == 0) sd0 = sd; else if (s == 1) sd1 = sd;
            else if (s == 2) sd2 = sd; else if (s == 3) sd3 = sd; else sd4 = sd;
        }

        for (int w2 = lane; w2 < 160; w2 += 64) bits[wid][w2] = 0u;
        __syncthreads();
        for (int e2 = lane; e2 < 125; e2 += 64) {
            int q = e2 / 25;
            int sd = (q == 0) ? sd0 : (q == 1) ? sd1 : (q == 2) ? sd2 : (q == 3) ? sd3 : sd4;
            int pt = nb[sd * KK + (e2 % 25)];
            atomicOr(&bits[wid][pt >> 5], 1u << (pt & 31));
        }
        __syncthreads();
        compact_bits_par(bits[wid], smv[wid], siv[wid], lane);
        for (int e2 = lane; e2 < 125; e2 += 64) {
            outMask[p * 125 + e2] = smv[wid][e2];
            outIdx[p * 125 + e2]  = siv[wid][e2];
        }
    } else {
        // ---------------- pc role ----------------
        int bid2 = bid - PP / 4;
        int ib = (bid2 & 7) * (PP / 4 / 8) + (bid2 >> 3);
        int i = ib * 4 + wid;

        double mysim = -1e300;
        if (lane < KK) {
            int nbs = nb[i * KK + lane];
            const float* crow = &pcn[(size_t)i * CC];
            const float* nrow = &pcn[(size_t)nbs * CC];
            double s0 = 0.0, s1 = 0.0, s2 = 0.0, s3 = 0.0;
#pragma unroll 8
            for (int c = 0; c < CC; c += 4) {
                float4 cv = *(const float4*)&crow[c];
                float4 nv = *(const float4*)&nrow[c];
                s0 += (double)cv.x * (double)nv.x;
                s1 += (double)cv.y * (double)nv.y;
                s2 += (double)cv.z * (double)nv.z;
                s3 += (double)cv.w * (double)nv.w;
            }
            mysim = (s0 + s1) + (s2 + s3);
        }
        double mx = mysim;
#pragma unroll
        for (int o = 1; o < 64; o <<= 1) mx = fmax(mx, __shfl_xor(mx, o));

        double e = 0.0;
        if (lane < KK) e = exp(mysim - mx);
        double sum = e;
#pragma unroll
        for (int o = 32; o; o >>= 1) sum += __shfl_xor(sum, o);
        double inv = 1.0 / sum;

        double selv = -1e300;
        if (lane < KK)
            selv = (lane == 0) ? (double)NEGV : (e * inv * bestPSd[nb[i * KK + lane]]);

        int tks[5]; tks[0] = 0;
        double sv = selv; int sk = (lane < KK) ? lane : 63;
#pragma unroll
        for (int s = 0; s < 4; ++s) {
            double bv = sv; int bk = sk;
#pragma unroll
            for (int o = 1; o < 64; o <<= 1) {
                double ov = __shfl_xor(bv, o);
                int ok = __shfl_xor(bk, o);
                if (ov > bv || (ov == bv && ok < bk)) { bv = ov; bk = ok; }
            }
            tks[s + 1] = bk;
            if (sk == bk) sv = -1e300;
        }

        int sd0, sd1, sd2, sd3, sd4;
#pragma unroll
        for (int s = 0; s < 5; ++s) {
            int nbs = nb[i * KK + tks[s]];
            int sd = bestPI[nbs];
            if (s == 0) sd0 = sd; else if (s == 1) sd1 = sd;
            else if (s == 2) sd2 = sd; else if (s == 3) sd3 = sd; else sd4 = sd;
        }

        for (int w2 = lane; w2 < 160; w2 += 64) bits[wid][w2] = 0u;
        __syncthreads();
        for (int e2 = lane; e2 < 125; e2 += 64) {
            int q = e2 / 25;
            int sd = (q == 0) ? sd0 : (q == 1) ? sd1 : (q == 2) ? sd2 : (q == 3) ? sd3 : sd4;
            int kk = e2 % 25;
            int r0 = sd >> 7, c0 = sd & 127;
            int r = min(max(r0 + kk / 5 - 2, 0), HH - 1);
            int c = min(max(c0 + kk % 5 - 2, 0), WW - 1);
            int pix = r * WW + c;
            atomicOr(&bits[wid][pix >> 5], 1u << (pix & 31));
        }
        __syncthreads();
        compact_bits_par(bits[wid], smv[wid], siv[wid], lane);
        for (int e2 = lane; e2 < 125; e2 += 64) {
            outMaskPc[i * 125 + e2] = smv[wid][e2];
            outIdxPc[i * 125 + e2]  = siv[wid][e2];
        }
    }
}

// ---------------- host ----------------------------------------------------------
extern "C" void kernel_launch(void* const* d_in, const int* in_sizes, int n_in,
                              void* d_out, int out_size, void* d_ws, size_t ws_size,
                              hipStream_t stream) {
    const float* imf = (const float*)d_in[0];
    const float* pcf = (const float*)d_in[1];
    const float* pts = (const float*)d_in[2];
    float* out = (float*)d_out;

    char* w = (char*)d_ws;
    double* bestSd  = (double*)w;  w += (size_t)PP * 8;
    double* bestPSd = (double*)w;  w += (size_t)NN * 8;
    double* rqv     = (double*)w;  w += (size_t)(PP + NN) * RSEGS * 8;
    float*  imn     = (float*)w;   w += (size_t)PP * CC * 4;
    float*  pcn     = (float*)w;   w += (size_t)NN * CC * 4;
    __half* imh     = (__half*)w;  w += (size_t)PP * CC * 2;
    __half* iml     = (__half*)w;  w += (size_t)PP * CC * 2;
    __half* pch     = (__half*)w;  w += (size_t)NN * CC * 2;
    __half* pcl     = (__half*)w;  w += (size_t)NN * CC * 2;
    float*  pval    = (float*)w;   w += (size_t)NSEG * PP * 4;
    float*  pv2     = (float*)w;   w += (size_t)NSEG * PP * 4;
    int*    pidx    = (int*)w;     w += (size_t)NSEG * PP * 4;
    float*  pvalT   = (float*)w;   w += (size_t)NRT * NN * 4;
    float*  pv2T    = (float*)w;   w += (size_t)NRT * NN * 4;
    int*    pidxT   = (int*)w;     w += (size_t)NRT * NN * 4;
    int*    rqi     = (int*)w;     w += (size_t)(PP + NN) * RSEGS * 4;
    int*    nb      = (int*)w;     w += (size_t)NN * KK * 4;
    int*    bestI   = (int*)w;     w += (size_t)PP * 4;
    int*    bestPI  = (int*)w;     w += (size_t)NN * 4;
    int*    list2   = (int*)w;     w += (size_t)(PP + NN) * 4;
    int*    cnt     = (int*)w;     w += 256;

    float* outSelect = out;                       // (25, 5120)
    float* outMask   = out + KK * PP;             // (5120, 125)
    float* outIdx    = outMask + PP * 125;        // (5120, 125)
    float* outIdxPc  = outIdx + PP * 125;         // (5120, 125)
    float* outMaskPc = outIdxPc + NN * 125;       // (5120, 125)

    k_prep<<<NRMB + NN, 256, 0, stream>>>(imf, pcf, pts, imn, pcn,
                                          imh, iml, pch, pcl, nb, cnt);
    k_rowmax<<<dim3(NRT, CSPL, 1), 256, 0, stream>>>(imh, iml, pch, pcl,
                                                     pval, pv2, pidx,
                                                     pvalT, pv2T, pidxT);
    k_reduce_exact<<<(PP + NN) / 4, 256, 0, stream>>>(pval, pv2, pidx,
                                                      pvalT, pv2T, pidxT, imn, pcn,
                                                      bestI, bestPI, bestSd, bestPSd,
                                                      list2, cnt);
    k_recheck64a<<<dim3(RSEGS, 256), 256, 0, stream>>>(imn, pcn, list2, cnt, rqv, rqi);
    k_recheck64b<<<(PP + NN) / 256, 256, 0, stream>>>(list2, cnt, rqv, rqi,
                                                      bestSd, bestI, bestPSd, bestPI);
    k_select_spot<<<2 * PP / 4, 256, 0, stream>>>(imn, pcn, nb, bestSd, bestI,
                                                  bestPSd, bestPI, outSelect,
                                                  outMask, outIdx, outMaskPc, outIdxPc);
}

// Round 31
// 171.432 us; speedup vs baseline: 1.0694x; 1.0694x over previous
//
#include <hip/hip_runtime.h>
#include <hip/hip_fp16.h>
#include <float.h>
#include <math.h>

#define HH 40
#define WW 128
#define PP 5120
#define NN 5120
#define CC 128
#define KK 25
#define SPOT 5
#define NEGV -1e8f

#define CSPL 8
#define NSEG 16
#define EPS  1e-4f
#define LOSC 2048.0f
#define RSEGS 16
#define RSEGL (NN / RSEGS)
#define NRMB ((PP + NN) / 4)     // normalize-role blocks in k_prep

typedef _Float16 half8 __attribute__((ext_vector_type(8)));
typedef float f32x4 __attribute__((ext_vector_type(4)));

// ---------------- K1+K2 fused: normalize (blocks 0..NRMB-1) || knn (rest) --------
__global__ __launch_bounds__(256) void k_prep(const float* __restrict__ imf,
                                              const float* __restrict__ pcf,
                                              const float* __restrict__ pts,
                                              float* __restrict__ imn, float* __restrict__ pcn,
                                              __half* __restrict__ imh, __half* __restrict__ iml,
                                              __half* __restrict__ pch, __half* __restrict__ pcl,
                                              int* __restrict__ nb, int* __restrict__ cnt) {
    __shared__ int hist[256];
    __shared__ int wsum2[2][4];
    __shared__ int wsum[4];
    __shared__ int wmin[4];
    __shared__ int s_b, s_need, s_cntLess;
    __shared__ unsigned long long sel[32];
    int t = threadIdx.x;
    int wid = t >> 6, lane = t & 63;

    if (blockIdx.x < NRMB) {
        // ---------------- normalize role ----------------
        if (blockIdx.x == 0 && t < 4) cnt[t] = 0;
        int row = blockIdx.x * 4 + wid;
        const float* src; float* dst; __half* dh; __half* dl; int r;
        if (row < PP) { src = imf; dst = imn; dh = imh; dl = iml; r = row; }
        else          { src = pcf; dst = pcn; dh = pch; dl = pcl; r = row - PP; }
        float2 v = *(const float2*)&src[r * CC + lane * 2];
        double ss = (double)v.x * (double)v.x + (double)v.y * (double)v.y;
#pragma unroll
        for (int o = 32; o; o >>= 1) ss += __shfl_xor(ss, o);
        double inv = 1.0 / fmax(sqrt(ss), 1e-12);
        float2 o2 = make_float2((float)((double)v.x * inv), (float)((double)v.y * inv));
        *(float2*)&dst[r * CC + lane * 2] = o2;
        __half hx = __float2half_rn(o2.x), hy = __float2half_rn(o2.y);
        float rx = o2.x - __half2float(hx), ry = o2.y - __half2float(hy);
        __half2 hh; hh.x = hx; hh.y = hy;
        __half2 ll; ll.x = __float2half_rn(rx * LOSC); ll.y = __float2half_rn(ry * LOSC);
        *(__half2*)&dh[r * CC + lane * 2] = hh;
        *(__half2*)&dl[r * CC + lane * 2] = ll;
        return;
    }

    // ---------------- knn role ----------------
    int i = blockIdx.x - NRMB;
    float px = pts[i * 3 + 0], py = pts[i * 3 + 1], pz = pts[i * 3 + 2];

    unsigned k[20];
#pragma unroll
    for (int e = 0; e < 20; ++e) {
        int j = e * 256 + t;
        float dx = __fsub_rn(px, pts[j * 3 + 0]);
        float dy = __fsub_rn(py, pts[j * 3 + 1]);
        float dz = __fsub_rn(pz, pts[j * 3 + 2]);
        float s = __fadd_rn(__fadd_rn(__fmul_rn(dx, dx), __fmul_rn(dy, dy)),
                            __fmul_rn(dz, dz));
        k[e] = __float_as_uint(s);
    }

    int need = KK;
    unsigned bpre = 0;
    for (int bit = 7; bit >= 0; --bit) {
        int c = 0;
        unsigned want = bpre << 1;
#pragma unroll
        for (int e = 0; e < 20; ++e)
            c += ((k[e] >> (24 + bit)) == want);
#pragma unroll
        for (int o = 32; o; o >>= 1) c += __shfl_xor(c, o);
        int par = bit & 1;
        if (lane == 0) wsum2[par][wid] = c;
        __syncthreads();
        int tot = wsum2[par][0] + wsum2[par][1] + wsum2[par][2] + wsum2[par][3];
        if (tot >= need) bpre = want;
        else { bpre = want | 1; need -= tot; }
    }
    unsigned prefix = bpre << 24;

    for (int l = 1; l < 4; ++l) {
        int shift = 24 - 8 * l;
        hist[t] = 0;
        __syncthreads();
        unsigned pmask = 0xFFFFFFFFu << (shift + 8);
#pragma unroll
        for (int e = 0; e < 20; ++e)
            if ((k[e] & pmask) == prefix)
                atomicAdd(&hist[(k[e] >> shift) & 255], 1);
        __syncthreads();
        int v = hist[t], c = v;
#pragma unroll
        for (int o = 1; o < 64; o <<= 1) {
            int u = __shfl_up(c, o);
            if (lane >= o) c += u;
        }
        if (lane == 63) wsum[wid] = c;
        __syncthreads();
        for (int wv = 0; wv < wid; ++wv) c += wsum[wv];
        int cex = c - v;
        if (cex < need && c >= need) { s_b = t; s_need = need - cex; }
        __syncthreads();
        prefix |= ((unsigned)s_b) << shift;
        need = s_need;
        __syncthreads();
    }

    unsigned K = prefix;
    int needK = need;

    if (t == 0) s_cntLess = 0;
    __syncthreads();
#pragma unroll
    for (int e = 0; e < 20; ++e) {
        if (k[e] < K) {
            int slot = atomicAdd(&s_cntLess, 1);
            if (slot < 32)
                sel[slot] = ((unsigned long long)k[e] << 32) | (unsigned)(e * 256 + t);
        }
    }
    __syncthreads();
    int nl = s_cntLess;

    if (t < nl) {
        unsigned long long mine = sel[t];
        int rk = 0;
        for (int s = 0; s < nl; ++s) rk += (sel[s] < mine);
        nb[i * KK + rk] = (int)(mine & 0xFFFFFFFFull);
    }

    unsigned tmask = 0;
#pragma unroll
    for (int e = 0; e < 20; ++e)
        if (k[e] == K) tmask |= 1u << e;

    for (int q = 0; q < needK; ++q) {
        int mi = tmask ? ((__ffs(tmask) - 1) * 256 + t) : 0x7fffffff;
#pragma unroll
        for (int o = 32; o; o >>= 1) mi = min(mi, __shfl_xor(mi, o));
        if (lane == 0) wmin[wid] = mi;
        __syncthreads();
        int g = min(min(wmin[0], wmin[1]), min(wmin[2], wmin[3]));
        if (t == 0) nb[i * KK + nl + q] = g;
        if ((g & 255) == t) tmask &= ~(1u << (g >> 8));
        __syncthreads();
    }
}

// ---------------- K3: split-fp16 MFMA screen (DMA dbuf, 32-col chunks) -----------
// r29 two-GEMM structure restored (r30's fused-transpose was neutral-regressive).
// OCCUPANCY FIX: 32-col chunks halve LDS 64KB->32KB -> 5 blocks/CU (was 2),
// 20 waves/CU for latency hiding. Same total MFMA, same swizzle, same DMA.
// Column partition between wcol partials changes; partials merge exactly in
// k_reduce_exact (disjoint top-2 merge), near-ties EPS-flagged -> fp64 recheck.
__global__ __launch_bounds__(256) void k_rowmax(const __half* __restrict__ imh,
                                                const __half* __restrict__ iml,
                                                const __half* __restrict__ pch,
                                                const __half* __restrict__ pcl,
                                                float* __restrict__ pval,
                                                float* __restrict__ pv2,
                                                int* __restrict__ pidx) {
    const __half* Ah = (blockIdx.z == 0) ? imh : pch;
    const __half* Al = (blockIdx.z == 0) ? iml : pcl;
    const __half* Bh = (blockIdx.z == 0) ? pch : imh;
    const __half* Bl = (blockIdx.z == 0) ? pcl : iml;
    __shared__ char sB[2 * 16384];     // [buf][Bh 8KB | Bl 8KB], 32 rows x 256B

    int t = threadIdx.x;
    int wave = t >> 6, l = t & 63;
    int wrow = wave >> 1, wcol = wave & 1;
    int lg = l >> 4, lc = l & 15;
    int rb = blockIdx.x * 64;
    const int segLen = NN / CSPL;      // 640
    const int nCh = segLen / 32;       // 20
    int segbase = blockIdx.y * segLen;
    int srow = l >> 4;                 // lane's row within a 4-row batch
    int sblk = l & 15;                 // lane's 16B block within a 256B row

    half8 Afh[2][4], Afl[2][4];
#pragma unroll
    for (int rt = 0; rt < 2; ++rt)
#pragma unroll
        for (int ks = 0; ks < 4; ++ks) {
            int row = rb + wrow * 32 + rt * 16 + lc;
            int ho = ks * 32 + lg * 8;
            Afh[rt][ks] = *(const half8*)&Ah[(size_t)row * CC + ho];
            Afl[rt][ks] = *(const half8*)&Al[(size_t)row * CC + ho];
        }

    float v1[2][4], v2[2][4]; int i1[2][4];
#pragma unroll
    for (int rt = 0; rt < 2; ++rt)
#pragma unroll
        for (int rg = 0; rg < 4; ++rg) { v1[rt][rg] = -1e30f; v2[rt][rg] = -1e30f; i1[rt][rg] = 0; }

    // DMA stage: wave wv fills rows [wv*8, wv*8+8) = 2 batches of 4 rows.
    auto stage = [&](int bufsel, int chbase) {
#pragma unroll
        for (int b = 0; b < 2; ++b) {
            int rbase = wave * 8 + b * 4;           // uniform within wave
            int r = rbase + srow;                   // per-lane row
            int gblk = sblk ^ (r & 7);              // inverse-swizzled source block
            __builtin_amdgcn_global_load_lds(
                (const __attribute__((address_space(1))) void*)
                    &Bh[(size_t)(chbase + r) * CC + gblk * 8],
                (__attribute__((address_space(3))) void*)
                    (sB + bufsel * 16384 + rbase * 256),
                16, 0, 0);
            __builtin_amdgcn_global_load_lds(
                (const __attribute__((address_space(1))) void*)
                    &Bl[(size_t)(chbase + r) * CC + gblk * 8],
                (__attribute__((address_space(3))) void*)
                    (sB + bufsel * 16384 + 8192 + rbase * 256),
                16, 0, 0);
        }
    };

    stage(0, segbase);
    __syncthreads();                   // buf0 ready

    int cur = 0;
    for (int c = 0; c < nCh; ++c) {
        if (c + 1 < nCh) stage(cur ^ 1, segbase + (c + 1) * 32);   // DMA in flight

        f32x4 aH[2], aX[2];
#pragma unroll
        for (int rt = 0; rt < 2; ++rt) {
            aH[rt] = (f32x4){0.f, 0.f, 0.f, 0.f};
            aX[rt] = (f32x4){0.f, 0.f, 0.f, 0.f};
        }

        const char* bufp = sB + cur * 16384;
#pragma unroll
        for (int ks = 0; ks < 4; ++ks) {
            int kb = ks * 64 + lg * 16;
            int row = wcol * 16 + lc;
            int off = row * 256 + (kb ^ ((row & 7) << 4));
            half8 bh = *(const half8*)(bufp + off);
            half8 bl = *(const half8*)(bufp + 8192 + off);
#pragma unroll
            for (int rt = 0; rt < 2; ++rt) {
                aH[rt] = __builtin_amdgcn_mfma_f32_16x16x32_f16(
                    Afh[rt][ks], bh, aH[rt], 0, 0, 0);
                aX[rt] = __builtin_amdgcn_mfma_f32_16x16x32_f16(
                    Afh[rt][ks], bl, aX[rt], 0, 0, 0);
                aX[rt] = __builtin_amdgcn_mfma_f32_16x16x32_f16(
                    Afl[rt][ks], bh, aX[rt], 0, 0, 0);
            }
        }

#pragma unroll
        for (int rt = 0; rt < 2; ++rt) {
            int col = segbase + c * 32 + wcol * 16 + lc;
#pragma unroll
            for (int rg = 0; rg < 4; ++rg) {
                float v = aH[rt][rg] + aX[rt][rg] * (1.0f / LOSC);
                bool gt = v > v1[rt][rg];
                v2[rt][rg] = gt ? v1[rt][rg] : fmaxf(v2[rt][rg], v);
                i1[rt][rg] = gt ? col : i1[rt][rg];
                v1[rt][rg] = gt ? v : v1[rt][rg];
            }
        }
        __syncthreads();   // releases cur reads AND completes next buf's DMA
        cur ^= 1;
    }

#pragma unroll
    for (int rt = 0; rt < 2; ++rt)
#pragma unroll
        for (int rg = 0; rg < 4; ++rg) {
            float a1 = v1[rt][rg], a2 = v2[rt][rg]; int ai = i1[rt][rg];
#pragma unroll
            for (int o = 1; o < 16; o <<= 1) {
                float o1 = __shfl_xor(a1, o);
                float o2v = __shfl_xor(a2, o);
                int   oi = __shfl_xor(ai, o);
                if (o1 > a1) { a2 = fmaxf(a1, o2v); a1 = o1; ai = oi; }
                else         { a2 = fmaxf(a2, o1); }
            }
            if (lc == 0) {
                int seg = blockIdx.y * 2 + wcol;
                size_t o = ((size_t)blockIdx.z * NSEG + seg) * PP
                         + rb + wrow * 32 + rt * 16 + lg * 4 + rg;
                pval[o] = a1; pv2[o] = a2; pidx[o] = ai;
            }
        }
}

// ---------------- K3b+K3e fused: wave-per-row partial-reduce + exact fp64 value --
__global__ void k_reduce_exact(const float* __restrict__ pval, const float* __restrict__ pv2,
                               const int* __restrict__ pidx,
                               const float* __restrict__ imn, const float* __restrict__ pcn,
                               int* __restrict__ bestI, int* __restrict__ bestPI,
                               double* __restrict__ bestSd, double* __restrict__ bestPSd,
                               int* __restrict__ list2, int* __restrict__ cnt) {
    int wid = threadIdx.x >> 6, lane = threadIdx.x & 63;
    int row = blockIdx.x * 4 + wid;
    int side = (row >= PP) ? 1 : 0;
    int r = side ? (row - PP) : row;
    size_t base = (size_t)side * NSEG * PP + r;

    float v1 = -1e30f, v2 = -1e30f; int i1 = 0x7fffffff;
    if (lane < NSEG) {
        v1 = pval[base + (size_t)lane * PP];
        v2 = pv2[base + (size_t)lane * PP];
        i1 = pidx[base + (size_t)lane * PP];
    }
#pragma unroll
    for (int o = 1; o < 16; o <<= 1) {
        float o1 = __shfl_xor(v1, o);
        float o2v = __shfl_xor(v2, o);
        int   oi = __shfl_xor(i1, o);
        if (o1 > v1) { v2 = fmaxf(v1, o2v); v1 = o1; i1 = oi; }
        else         { v2 = fmaxf(v2, o1); }
    }
    int bi = __shfl(i1, 0);
    float b1 = __shfl(v1, 0), b2 = __shfl(v2, 0);

    const float* A = side ? pcn : imn;
    const float* B = side ? imn : pcn;
    float2 av = *(const float2*)&A[(size_t)r * CC + lane * 2];
    float2 bv = *(const float2*)&B[(size_t)bi * CC + lane * 2];
    double s = (double)av.x * (double)bv.x + (double)av.y * (double)bv.y;
#pragma unroll
    for (int o = 32; o; o >>= 1) s += __shfl_xor(s, o);

    if (lane == 0) {
        if (side == 0) { bestI[r] = bi; bestSd[r] = s; }
        else           { bestPI[r] = bi; bestPSd[r] = s; }
        if (b1 - b2 < EPS) {
            int slot = atomicAdd(&cnt[0], 1);
            list2[slot] = r | (side << 16);
        }
    }
}

// ---------------- K3f-a: fp64 repair, split 16 column-segments per flagged row ---
__global__ void k_recheck64a(const float* __restrict__ imn, const float* __restrict__ pcn,
                             const int* __restrict__ list2, const int* __restrict__ cnt,
                             double* __restrict__ rqv, int* __restrict__ rqi) {
    __shared__ double ad[CC];
    __shared__ double rv[4];
    __shared__ int    ri[4];
    int seg = blockIdx.x, t = threadIdx.x;
    int wid = t >> 6, lane = t & 63;
    int total = cnt[0];
    for (int e = blockIdx.y; e < total; e += gridDim.y) {
        __syncthreads();
        int ent = list2[e];
        int r = ent & 0xffff, side = ent >> 16;
        const float* Arow = (side == 0 ? imn : pcn) + (size_t)r * CC;
        const float* B    = (side == 0 ? pcn : imn);
        if (t < CC) ad[t] = (double)Arow[t];
        __syncthreads();
        double bv = -1e300; int bi = 0x7fffffff;
        for (int j = seg * RSEGL + t; j < (seg + 1) * RSEGL; j += 256) {
            double s0 = 0.0, s1 = 0.0, s2 = 0.0, s3 = 0.0;
#pragma unroll 8
            for (int c4 = 0; c4 < CC / 4; ++c4) {
                float4 b = *(const float4*)&B[(size_t)j * CC + c4 * 4];
                s0 += ad[c4 * 4 + 0] * (double)b.x;
                s1 += ad[c4 * 4 + 1] * (double)b.y;
                s2 += ad[c4 * 4 + 2] * (double)b.z;
                s3 += ad[c4 * 4 + 3] * (double)b.w;
            }
            double s = (s0 + s1) + (s2 + s3);
            if (s > bv || (s == bv && j < bi)) { bv = s; bi = j; }
        }
#pragma unroll
        for (int o = 32; o; o >>= 1) {
            double ov = __shfl_xor(bv, o); int oi = __shfl_xor(bi, o);
            if (ov > bv || (ov == bv && oi < bi)) { bv = ov; bi = oi; }
        }
        if (lane == 0) { rv[wid] = bv; ri[wid] = bi; }
        __syncthreads();
        if (t == 0) {
            for (int wv = 1; wv < 4; ++wv)
                if (rv[wv] > bv || (rv[wv] == bv && ri[wv] < bi)) { bv = rv[wv]; bi = ri[wv]; }
            rqv[(size_t)e * RSEGS + seg] = bv;
            rqi[(size_t)e * RSEGS + seg] = bi;
        }
        __syncthreads();
    }
}

// ---------------- K3f-b: reduce the 16 segment partials per entry ----------------
__global__ void k_recheck64b(const int* __restrict__ list2, const int* __restrict__ cnt,
                             const double* __restrict__ rqv, const int* __restrict__ rqi,
                             double* __restrict__ bestSd, int* __restrict__ bestI,
                             double* __restrict__ bestPSd, int* __restrict__ bestPI) {
    int e = blockIdx.x * 256 + threadIdx.x;
    if (e >= cnt[0]) return;
    double bv = rqv[(size_t)e * RSEGS]; int bi = rqi[(size_t)e * RSEGS];
#pragma unroll 4
    for (int s = 1; s < RSEGS; ++s) {
        double ov = rqv[(size_t)e * RSEGS + s]; int oi = rqi[(size_t)e * RSEGS + s];
        if (ov > bv || (ov == bv && oi < bi)) { bv = ov; bi = oi; }
    }
    int ent = list2[e];
    int r = ent & 0xffff, side = ent >> 16;
    if (side == 0) { bestSd[r] = bv; bestI[r] = bi; }
    else           { bestPSd[r] = bv; bestPI[r] = bi; }
}

// ---------------- WAVE-PARALLEL bitmap -> stable top-125 compaction --------------
__device__ __forceinline__ void compact_bits_par(const unsigned* bits,
                                                 float* __restrict__ sm,
                                                 float* __restrict__ si, int lane) {
    unsigned w0 = bits[lane];
    unsigned w1 = bits[64 + lane];
    unsigned w2 = (lane < 32) ? bits[128 + lane] : 0u;
    int c0 = __popc(w0), c1 = __popc(w1), c2 = __popc(w2);
    int s0 = c0, s1 = c1, s2 = c2;
#pragma unroll
    for (int o = 1; o < 64; o <<= 1) {
        int u0 = __shfl_up(s0, o); if (lane >= o) s0 += u0;
        int u1 = __shfl_up(s1, o); if (lane >= o) s1 += u1;
        int u2 = __shfl_up(s2, o); if (lane >= o) s2 += u2;
    }
    int tot0 = __shfl(s0, 63);
    int tot1 = __shfl(s1, 63);
    int tot2 = __shfl(s2, 31);
    int nl = tot0 + tot1 + tot2;
    int e0 = s0 - c0;
    int e1 = tot0 + (s1 - c1);
    int e2 = tot0 + tot1 + (s2 - c2);

    {
        int base = e0; unsigned word = w0; int wi = lane;
        while (word) { int pos = __ffs(word) - 1;
            si[base] = (float)(wi * 32 + pos); sm[base] = 1.0f; word &= word - 1; ++base; }
        base = e1; word = w1; wi = 64 + lane;
        while (word) { int pos = __ffs(word) - 1;
            si[base] = (float)(wi * 32 + pos); sm[base] = 1.0f; word &= word - 1; ++base; }
        if (lane < 32) {
            base = e2; word = w2; wi = 128 + lane;
            while (word) { int pos = __ffs(word) - 1;
                si[base] = (float)(wi * 32 + pos); sm[base] = 1.0f; word &= word - 1; ++base; }
        }
    }
    {
        int wi = lane; int base = nl + 32 * wi - e0; unsigned word = ~w0;
        while (word && base < 125) { int pos = __ffs(word) - 1;
            si[base] = (float)(wi * 32 + pos); sm[base] = 0.0f; word &= word - 1; ++base; }
        wi = 64 + lane; base = nl + 32 * wi - e1; word = ~w1;
        while (word && base < 125) { int pos = __ffs(word) - 1;
            si[base] = (float)(wi * 32 + pos); sm[base] = 0.0f; word &= word - 1; ++base; }
        if (lane < 32) {
            wi = 128 + lane; base = nl + 32 * wi - e2; word = ~w2;
            while (word && base < 125) { int pos = __ffs(word) - 1;
                si[base] = (float)(wi * 32 + pos); sm[base] = 0.0f; word &= word - 1; ++base; }
        }
    }
}

// ---------------- K4..K7 fused: select + spot ------------------------------------
__global__ void k_select_spot(const float* __restrict__ imn, const float* __restrict__ pcn,
                              const int* __restrict__ nb,
                              const double* __restrict__ bestSd, const int* __restrict__ bestI,
                              const double* __restrict__ bestPSd, const int* __restrict__ bestPI,
                              float* __restrict__ outSelect,
                              float* __restrict__ outMask, float* __restrict__ outIdx,
                              float* __restrict__ outMaskPc, float* __restrict__ outIdxPc) {
    __shared__ unsigned bits[4][160];
    __shared__ float smv[4][125];
    __shared__ float siv[4][125];
    int t = threadIdx.x;
    int wid = t >> 6, lane = t & 63;
    int bid = blockIdx.x;

    if (bid < PP / 4) {
        // ---------------- image role ----------------
        int pb = (bid & 7) * (PP / 4 / 8) + (bid >> 3);   // XCD-chunked
        int p = pb * 4 + wid;
        int h = p >> 7, w = p & 127;

        double mysim = -1e300;
        if (lane < KK) {
            int di = lane / 5 - 2, dj = lane % 5 - 2;
            int hc = min(max(h + di, 0), HH - 1);
            int wc = min(max(w + dj, 0), WW - 1);
            const float* crow = &imn[(size_t)p * CC];
            const float* nrow = &imn[(size_t)(hc * WW + wc) * CC];
            double s0 = 0.0, s1 = 0.0, s2 = 0.0, s3 = 0.0;
#pragma unroll 8
            for (int c = 0; c < CC; c += 4) {
                float4 cv = *(const float4*)&crow[c];
                float4 nv = *(const float4*)&nrow[c];
                s0 += (double)cv.x * (double)nv.x;
                s1 += (double)cv.y * (double)nv.y;
                s2 += (double)cv.z * (double)nv.z;
                s3 += (double)cv.w * (double)nv.w;
            }
            mysim = (s0 + s1) + (s2 + s3);
        }
        double mx = mysim;
#pragma unroll
        for (int o = 1; o < 64; o <<= 1) mx = fmax(mx, __shfl_xor(mx, o));

        double e = 0.0;
        if (lane < KK) e = exp(mysim - mx);
        double sum = e;
#pragma unroll
        for (int o = 32; o; o >>= 1) sum += __shfl_xor(sum, o);
        double inv = 1.0 / sum;

        double selv = -1e300;
        if (lane < KK) {
            int di = lane / 5 - 2, dj = lane % 5 - 2;
            int h2 = h + di, w2 = w + dj;
            bool valid = (h2 >= 0 && h2 < HH && w2 >= 0 && w2 < WW);
            int hc = min(max(h2, 0), HH - 1), wc = min(max(w2, 0), WW - 1);
            double conf = bestSd[hc * WW + wc];
            double so = valid ? (e * inv * conf) : (double)NEGV;
            outSelect[lane * PP + p] = (float)so;
            selv = (lane == 12) ? (double)NEGV : so;
        }

        int tks[5]; tks[0] = 12;
        double sv = selv; int sk = (lane < KK) ? lane : 63;
#pragma unroll
        for (int s = 0; s < 4; ++s) {
            double bv = sv; int bk = sk;
#pragma unroll
            for (int o = 1; o < 64; o <<= 1) {
                double ov = __shfl_xor(bv, o);
                int ok = __shfl_xor(bk, o);
                if (ov > bv || (ov == bv && ok < bk)) { bv = ov; bk = ok; }
            }
            tks[s + 1] = bk;
            if (sk == bk) sv = -1e300;
        }

        int sd0, sd1, sd2, sd3, sd4;
#pragma unroll
        for (int s = 0; s < 5; ++s) {
            int k = tks[s];
            int di = k / 5 - 2, dj = k % 5 - 2;
            int h2 = h + di, w2 = w + dj;
            int pix = (h2 >= 0 && h2 < HH && w2 >= 0 && w2 < WW) ? (h2 * WW + w2) : -1;
            pix = min(max(pix, 0), PP - 1);
            int sd = bestI[pix];
            if (s == 0) sd0 = sd; else if (s == 1) sd1 = sd;
            else if (s == 2) sd2 = sd; else if (s == 3) sd3 = sd; else sd4 = sd;
        }

        for (int w2 = lane; w2 < 160; w2 += 64) bits[wid][w2] = 0u;
        __syncthreads();
        for (int e2 = lane; e2 < 125; e2 += 64) {
            int q = e2 / 25;
            int sd = (q == 0) ? sd0 : (q == 1) ? sd1 : (q == 2) ? sd2 : (q == 3) ? sd3 : sd4;
            int pt = nb[sd * KK + (e2 % 25)];
            atomicOr(&bits[wid][pt >> 5], 1u << (pt & 31));
        }
        __syncthreads();
        compact_bits_par(bits[wid], smv[wid], siv[wid], lane);
        for (int e2 = lane; e2 < 125; e2 += 64) {
            outMask[p * 125 + e2] = smv[wid][e2];
            outIdx[p * 125 + e2]  = siv[wid][e2];
        }
    } else {
        // ---------------- pc role ----------------
        int bid2 = bid - PP / 4;
        int ib = (bid2 & 7) * (PP / 4 / 8) + (bid2 >> 3);
        int i = ib * 4 + wid;

        double mysim = -1e300;
        if (lane < KK) {
            int nbs = nb[i * KK + lane];
            const float* crow = &pcn[(size_t)i * CC];
            const float* nrow = &pcn[(size_t)nbs * CC];
            double s0 = 0.0, s1 = 0.0, s2 = 0.0, s3 = 0.0;
#pragma unroll 8
            for (int c = 0; c < CC; c += 4) {
                float4 cv = *(const float4*)&crow[c];
                float4 nv = *(const float4*)&nrow[c];
                s0 += (double)cv.x * (double)nv.x;
                s1 += (double)cv.y * (double)nv.y;
                s2 += (double)cv.z * (double)nv.z;
                s3 += (double)cv.w * (double)nv.w;
            }
            mysim = (s0 + s1) + (s2 + s3);
        }
        double mx = mysim;
#pragma unroll
        for (int o = 1; o < 64; o <<= 1) mx = fmax(mx, __shfl_xor(mx, o));

        double e = 0.0;
        if (lane < KK) e = exp(mysim - mx);
        double sum = e;
#pragma unroll
        for (int o = 32; o; o >>= 1) sum += __shfl_xor(sum, o);
        double inv = 1.0 / sum;

        double selv = -1e300;
        if (lane < KK)
            selv = (lane == 0) ? (double)NEGV : (e * inv * bestPSd[nb[i * KK + lane]]);

        int tks[5]; tks[0] = 0;
        double sv = selv; int sk = (lane < KK) ? lane : 63;
#pragma unroll
        for (int s = 0; s < 4; ++s) {
            double bv = sv; int bk = sk;
#pragma unroll
            for (int o = 1; o < 64; o <<= 1) {
                double ov = __shfl_xor(bv, o);
                int ok = __shfl_xor(bk, o);
                if (ov > bv || (ov == bv && ok < bk)) { bv = ov; bk = ok; }
            }
            tks[s + 1] = bk;
            if (sk == bk) sv = -1e300;
        }

        int sd0, sd1, sd2, sd3, sd4;
#pragma unroll
        for (int s = 0; s < 5; ++s) {
            int nbs = nb[i * KK + tks[s]];
            int sd = bestPI[nbs];
            if (s == 0) sd0 = sd; else if (s == 1) sd1 = sd;
            else if (s == 2) sd2 = sd; else if (s == 3) sd3 = sd; else sd4 = sd;
        }

        for (int w2 = lane; w2 < 160; w2 += 64) bits[wid][w2] = 0u;
        __syncthreads();
        for (int e2 = lane; e2 < 125; e2 += 64) {
            int q = e2 / 25;
            int sd = (q == 0) ? sd0 : (q == 1) ? sd1 : (q == 2) ? sd2 : (q == 3) ? sd3 : sd4;
            int kk = e2 % 25;
            int r0 = sd >> 7, c0 = sd & 127;
            int r = min(max(r0 + kk / 5 - 2, 0), HH - 1);
            int c = min(max(c0 + kk % 5 - 2, 0), WW - 1);
            int pix = r * WW + c;
            atomicOr(&bits[wid][pix >> 5], 1u << (pix & 31));
        }
        __syncthreads();
        compact_bits_par(bits[wid], smv[wid], siv[wid], lane);
        for (int e2 = lane; e2 < 125; e2 += 64) {
            outMaskPc[i * 125 + e2] = smv[wid][e2];
            outIdxPc[i * 125 + e2]  = siv[wid][e2];
        }
    }
}

// ---------------- host ----------------------------------------------------------
extern "C" void kernel_launch(void* const* d_in, const int* in_sizes, int n_in,
                              void* d_out, int out_size, void* d_ws, size_t ws_size,
                              hipStream_t stream) {
    const float* imf = (const float*)d_in[0];
    const float* pcf = (const float*)d_in[1];
    const float* pts = (const float*)d_in[2];
    float* out = (float*)d_out;

    char* w = (char*)d_ws;
    double* bestSd  = (double*)w;  w += (size_t)PP * 8;
    double* bestPSd = (double*)w;  w += (size_t)NN * 8;
    double* rqv     = (double*)w;  w += (size_t)(PP + NN) * RSEGS * 8;
    float*  imn     = (float*)w;   w += (size_t)PP * CC * 4;
    float*  pcn     = (float*)w;   w += (size_t)NN * CC * 4;
    __half* imh     = (__half*)w;  w += (size_t)PP * CC * 2;
    __half* iml     = (__half*)w;  w += (size_t)PP * CC * 2;
    __half* pch     = (__half*)w;  w += (size_t)NN * CC * 2;
    __half* pcl     = (__half*)w;  w += (size_t)NN * CC * 2;
    float*  pval    = (float*)w;   w += (size_t)2 * NSEG * PP * 4;
    float*  pv2     = (float*)w;   w += (size_t)2 * NSEG * PP * 4;
    int*    pidx    = (int*)w;     w += (size_t)2 * NSEG * PP * 4;
    int*    rqi     = (int*)w;     w += (size_t)(PP + NN) * RSEGS * 4;
    int*    nb      = (int*)w;     w += (size_t)NN * KK * 4;
    int*    bestI   = (int*)w;     w += (size_t)PP * 4;
    int*    bestPI  = (int*)w;     w += (size_t)NN * 4;
    int*    list2   = (int*)w;     w += (size_t)(PP + NN) * 4;
    int*    cnt     = (int*)w;     w += 256;

    float* outSelect = out;                       // (25, 5120)
    float* outMask   = out + KK * PP;             // (5120, 125)
    float* outIdx    = outMask + PP * 125;        // (5120, 125)
    float* outIdxPc  = outIdx + PP * 125;         // (5120, 125)
    float* outMaskPc = outIdxPc + NN * 125;       // (5120, 125)

    k_prep<<<NRMB + NN, 256, 0, stream>>>(imf, pcf, pts, imn, pcn,
                                          imh, iml, pch, pcl, nb, cnt);
    k_rowmax<<<dim3(PP / 64, CSPL, 2), 256, 0, stream>>>(imh, iml, pch, pcl,
                                                         pval, pv2, pidx);
    k_reduce_exact<<<(PP + NN) / 4, 256, 0, stream>>>(pval, pv2, pidx, imn, pcn,
                                                      bestI, bestPI, bestSd, bestPSd,
                                                      list2, cnt);
    k_recheck64a<<<dim3(RSEGS, 256), 256, 0, stream>>>(imn, pcn, list2, cnt, rqv, rqi);
    k_recheck64b<<<(PP + NN) / 256, 256, 0, stream>>>(list2, cnt, rqv, rqi,
                                                      bestSd, bestI, bestPSd, bestPI);
    k_select_spot<<<2 * PP / 4, 256, 0, stream>>>(imn, pcn, nb, bestSd, bestI,
                                                  bestPSd, bestPI, outSelect,
                                                  outMask, outIdx, outMaskPc, outIdxPc);
}